// Round 2
// baseline (89.369 us; speedup 1.0000x reference)
//
#include <hip/hip_runtime.h>

#define NROT 256
#define NB   8192

// ---------------------------------------------------------------------------
// Workspace layout (bytes):
//   [0,       1048576)   Rg: 4 group products (4 x 256x256 f32)
//   [1048576, 1310720)   R : final merged 256x256 f32
// ---------------------------------------------------------------------------

// ---------------------------------------------------------------------------
// K1: partial rotation products, 4 groups of 64 rounds, schedule + sincos
// computed INLINE (k_prep fused away).  One wave per block, 4 columns in LDS,
// wave-synchronous (no barriers).
// Two-level prefetch ring, all off the LDS dependency chain:
//   theta ring (depth 4): global theta loads issued 4 rounds ahead
//   cs ring    (depth 2): sincos computed 2 rounds ahead (theta arrived)
// Rounds >= 255 (group-3 pad + ring overrun): theta=0, pair (0,1)
//   -> sincos(0)=(0,1) -> exact identity rotation through the normal path.
// LDS rows padded: row m stored at m + (m>>3)  (breaks the mod-8 bank
// aliasing of float4 rows: 8-way conflicts -> <=4-way).
// ---------------------------------------------------------------------------
__device__ __forceinline__ int bm(int m) { return m + (m >> 3); }

// schedule for (round rr, pair k): returns packed (i | j<<16) and theta value
__device__ __forceinline__ void sched_load(const float* __restrict__ thetas,
                                           int rr, int k, float* th, int* ab) {
    if (rr >= 255) {            // pad: identity rotation on rows (0,1)
        *th = 0.0f;
        *ab = 0 | (1 << 16);
        return;
    }
    int i, j;
    if (k == 0) {
        i = 0;
        j = 255 - rr;
    } else {
        int m1 = k - 1 - rr;    if (m1 < 0) m1 += 255;
        int m2 = 254 - k - rr;  if (m2 < 0) m2 += 255;
        int v1 = m1 + 1, v2 = m2 + 1;
        i = v1 < v2 ? v1 : v2;
        j = v1 < v2 ? v2 : v1;
    }
    int tix = i * 256 - (i * (i + 1)) / 2 + (j - i - 1);
    *th = thetas[tix];          // load issued here; waited on 2 rounds later
    *ab = i | (j << 16);
}

template <int ROFF>
__device__ __forceinline__ void rot_rounds64(const float* __restrict__ thetas,
                                             int l, float4* buf) {
    // theta ring (depth 4) and cs ring (depth 2), 2 pairs per lane
    float th0[4], th1[4];
    int   ab0[4], ab1[4];
    float c0r[2], s0r[2], c1r[2], s1r[2];
    int   pa0[2], pb0[2], pa1[2], pb1[2];

#pragma unroll
    for (int d = 0; d < 4; ++d) {
        sched_load(thetas, ROFF + d, 2 * l,     &th0[d], &ab0[d]);
        sched_load(thetas, ROFF + d, 2 * l + 1, &th1[d], &ab1[d]);
    }
#pragma unroll
    for (int d = 0; d < 2; ++d) {           // cs for rounds ROFF, ROFF+1
        sincosf(th0[d], &s0r[d], &c0r[d]);
        sincosf(th1[d], &s1r[d], &c1r[d]);
        pa0[d] = ab0[d] & 0xffff; pb0[d] = ab0[d] >> 16;
        pa1[d] = ab1[d] & 0xffff; pb1[d] = ab1[d] >> 16;
    }

#pragma unroll 4
    for (int it = 0; it < 64; ++it) {
        const int s2 = it & 1;               // cs ring slot (static, unroll 4)
        const int s4 = it & 3;               // theta ring slot (static)
        float C0 = c0r[s2], S0 = s0r[s2];
        float C1 = c1r[s2], S1 = s1r[s2];
        int a0 = pa0[s2], b0 = pb0[s2];
        int a1 = pa1[s2], b1 = pb1[s2];

        // refill theta ring: round it+4 (slot s4 just freed)
        sched_load(thetas, ROFF + it + 4, 2 * l,     &th0[s4], &ab0[s4]);
        sched_load(thetas, ROFF + it + 4, 2 * l + 1, &th1[s4], &ab1[s4]);
        // compute cs for round it+2 (theta loaded at it-2, long arrived)
        {
            const int sn = (it + 2) & 3;
            sincosf(th0[sn], &s0r[s2], &c0r[s2]);
            sincosf(th1[sn], &s1r[s2], &c1r[s2]);
            pa0[s2] = ab0[sn] & 0xffff; pb0[s2] = ab0[sn] >> 16;
            pa1[s2] = ab1[sn] & 0xffff; pb1[s2] = ab1[sn] >> 16;
        }

        // --- the LDS dependency chain ---
        float4 ra0 = buf[bm(a0)], rb0 = buf[bm(b0)];
        float4 ra1 = buf[bm(a1)], rb1 = buf[bm(b1)];
        float4 na0, nb0, na1, nb1;
        na0.x = C0 * ra0.x - S0 * rb0.x;
        na0.y = C0 * ra0.y - S0 * rb0.y;
        na0.z = C0 * ra0.z - S0 * rb0.z;
        na0.w = C0 * ra0.w - S0 * rb0.w;
        nb0.x = S0 * ra0.x + C0 * rb0.x;
        nb0.y = S0 * ra0.y + C0 * rb0.y;
        nb0.z = S0 * ra0.z + C0 * rb0.z;
        nb0.w = S0 * ra0.w + C0 * rb0.w;
        na1.x = C1 * ra1.x - S1 * rb1.x;
        na1.y = C1 * ra1.y - S1 * rb1.y;
        na1.z = C1 * ra1.z - S1 * rb1.z;
        na1.w = C1 * ra1.w - S1 * rb1.w;
        nb1.x = S1 * ra1.x + C1 * rb1.x;
        nb1.y = S1 * ra1.y + C1 * rb1.y;
        nb1.z = S1 * ra1.z + C1 * rb1.z;
        nb1.w = S1 * ra1.w + C1 * rb1.w;
        buf[bm(a0)] = na0; buf[bm(b0)] = nb0;
        buf[bm(a1)] = na1; buf[bm(b1)] = nb1;
    }
}

__global__ __launch_bounds__(64) void k_rot(const float* __restrict__ thetas,
                                            float* __restrict__ Rg) {
    __shared__ float4 buf[292];                  // 256 rows + mod-8 padding
    int l   = threadIdx.x;                       // 0..63, one wave per block
    int grp = blockIdx.y;                        // 0..3
    int c0  = blockIdx.x * 4;                    // this block's 4 columns
#pragma unroll
    for (int q = 0; q < 4; ++q) {
        int m = l * 4 + q;
        float4 v = make_float4(0.f, 0.f, 0.f, 0.f);
        if (m == c0)     v.x = 1.f;
        if (m == c0 + 1) v.y = 1.f;
        if (m == c0 + 2) v.z = 1.f;
        if (m == c0 + 3) v.w = 1.f;
        buf[bm(m)] = v;                          // identity columns
    }
    if      (grp == 0) rot_rounds64<0>(thetas, l, buf);
    else if (grp == 1) rot_rounds64<64>(thetas, l, buf);
    else if (grp == 2) rot_rounds64<128>(thetas, l, buf);
    else               rot_rounds64<192>(thetas, l, buf);

    float* Rout = Rg + grp * (256 * 256);
#pragma unroll
    for (int q = 0; q < 4; ++q) {
        int m = l * 4 + q;
        *(float4*)(Rout + m * 256 + c0) = buf[bm(m)];
    }
}

// ---------------------------------------------------------------------------
// K2: fused 3-stage merge  R = G3 * G2 * G1 * G0.
// 128 blocks x 256 threads; block owns output rows {2b, 2b+1}.
// Wave w = row (w>>1), k-half (w&1).  Per stage: v_row . M  with the row
// vector broadcast from LDS, M streamed from L2 (coalesced float4), k split
// across 2 waves, partials combined in LDS.  3 stages sequential in-block:
// saves one kernel launch + round trip vs the 2-level tree.
// ---------------------------------------------------------------------------
__global__ __launch_bounds__(256) void k_merge4(const float* __restrict__ Rg,
                                                float* __restrict__ R) {
    __shared__ float vcur[2][256];   // current row vectors (2 rows)
    __shared__ float pacc[4][256];   // per-wave partial sums
    int t = threadIdx.x;
    int w = t >> 6;                  // wave 0..3
    int l = t & 63;
    int row  = w >> 1;               // 0/1 within block
    int half = w & 1;                // k half
    int r0 = blockIdx.x * 2;         // global output rows r0, r0+1

    // init: v = rows of G3
    if (t < 128) {
        int rr = t >> 6, k4 = (t & 63) * 4;
        *(float4*)&vcur[rr][k4] =
            *(const float4*)(Rg + 3 * 65536 + (r0 + rr) * 256 + k4);
    }
    __syncthreads();

    for (int g = 2; g >= 0; --g) {
        const float* A = Rg + g * 65536;
        int kbase = half * 128;
        float4 acc = make_float4(0.f, 0.f, 0.f, 0.f);
#pragma unroll 8
        for (int kk = 0; kk < 128; ++kk) {
            float  s = vcur[row][kbase + kk];              // LDS broadcast
            float4 a = *(const float4*)(A + (kbase + kk) * 256 + l * 4);
            acc.x += s * a.x; acc.y += s * a.y;
            acc.z += s * a.z; acc.w += s * a.w;
        }
        *(float4*)&pacc[w][l * 4] = acc;
        __syncthreads();
        if (t < 128) {
            int rr = t >> 6, c4 = (t & 63) * 4;
            float4 p0 = *(float4*)&pacc[rr * 2 + 0][c4];
            float4 p1 = *(float4*)&pacc[rr * 2 + 1][c4];
            float4 sum = make_float4(p0.x + p1.x, p0.y + p1.y,
                                     p0.z + p1.z, p0.w + p1.w);
            if (g > 0) *(float4*)&vcur[rr][c4] = sum;
            else       *(float4*)(R + (r0 + rr) * 256 + c4) = sum;
        }
        __syncthreads();
    }
}

// ---------------------------------------------------------------------------
// K3: out = R * X  (256x256 @ 256x8192), fp32 vector GEMM.
// Block: 512 threads = 8 waves; tile 64 rows x 128 cols.  A via wave-uniform
// scalar loads (SMEM pipe), X double-buffered in LDS via global_load_lds
// width 16.  1 ds_read_b64 per 16 FMAs -> VALU-bound (~6.8 us floor).
// ---------------------------------------------------------------------------
__global__ __launch_bounds__(512) void k_gemm(const float* __restrict__ R,
                                              const float* __restrict__ X,
                                              float* __restrict__ out) {
    __shared__ __align__(16) float Xs[2][32][128];   // 2 x 16 KB k-chunks
    int t  = threadIdx.x;
    int w  = t >> 6;                                 // wave 0..7
    int l  = t & 63;
    int n0 = blockIdx.x * 128;                       // 64 col-groups
    int m0 = blockIdx.y * 64;                        // 4 row-groups
    int iw = __builtin_amdgcn_readfirstlane(m0 + w * 8);
    const float* Ra = R + iw * 256;                  // wave's 8 A-rows

    float2 acc[8];
#pragma unroll
    for (int r = 0; r < 8; ++r) acc[r] = make_float2(0.f, 0.f);

    auto stage = [&](int bi, int kc) {
        int k0  = kc * 32;
        int kkb = w * 4;
#pragma unroll
        for (int p = 0; p < 2; ++p) {
            int row = kkb + p * 2 + (l >> 5);
            int col = (l & 31) * 4;
            const float* src = X + (size_t)(k0 + row) * NB + n0 + col;
            __builtin_amdgcn_global_load_lds(
                (const __attribute__((address_space(1))) unsigned int*)src,
                (__attribute__((address_space(3))) unsigned int*)&Xs[bi][kkb + p * 2][0],
                16, 0, 0);
        }
    };

    stage(0, 0);
    __syncthreads();                                  // implies vmcnt(0) drain
    int buf = 0;
    for (int kc = 0; kc < 8; ++kc) {
        if (kc < 7) stage(buf ^ 1, kc + 1);           // prefetch next chunk
#pragma unroll
        for (int k4 = 0; k4 < 8; ++k4) {              // 4-k sub-chunks
            float4 ar[8];
#pragma unroll
            for (int r = 0; r < 8; ++r)               // uniform addr -> s_load
                ar[r] = *(const float4*)(Ra + r * 256 + kc * 32 + k4 * 4);
#pragma unroll
            for (int q = 0; q < 4; ++q) {
                float2 x = *(const float2*)&Xs[buf][k4 * 4 + q][l * 2];
#pragma unroll
                for (int r = 0; r < 8; ++r) {
                    float av = (q == 0) ? ar[r].x : (q == 1) ? ar[r].y
                             : (q == 2) ? ar[r].z : ar[r].w;
                    acc[r].x += av * x.x;
                    acc[r].y += av * x.y;
                }
            }
        }
        __syncthreads();                              // staged chunk now visible
        buf ^= 1;
    }
#pragma unroll
    for (int r = 0; r < 8; ++r) {
        *(float2*)(out + (size_t)(iw + r) * NB + n0 + l * 2) = acc[r];
    }
}

// ---------------------------------------------------------------------------
extern "C" void kernel_launch(void* const* d_in, const int* in_sizes, int n_in,
                              void* d_out, int out_size, void* d_ws, size_t ws_size,
                              hipStream_t stream) {
    const float* X      = (const float*)d_in[0];
    const float* thetas = (const float*)d_in[1];
    float* out = (float*)d_out;
    char*  ws  = (char*)d_ws;

    float* Rg = (float*)ws;                    // 4 x 256x256
    float* R  = (float*)(ws + 1048576);        // merged 256x256

    k_rot   <<<dim3(64, 4), dim3(64),  0, stream>>>(thetas, Rg);
    k_merge4<<<dim3(128),   dim3(256), 0, stream>>>(Rg, R);
    k_gemm  <<<dim3(64, 4), dim3(512), 0, stream>>>(R, X, out);
}

// Round 3
// 67.040 us; speedup vs baseline: 1.3331x; 1.3331x over previous
//
#include <hip/hip_runtime.h>

#define NROT 256
#define NB   8192
#define TBL_ROUNDS 264   // 255 real rounds + identity padding for prefetch ring

// ---------------------------------------------------------------------------
// Workspace layout (bytes):
//   [0,       540672)    cs/ij table: 264 rounds x 128 x float4
//   [540672,  1589248)   Rg: 4 group products (4 x 256x256 f32)
//   [1589248, 1851392)   R : final merged 256x256 f32
// ---------------------------------------------------------------------------

// ---------------------------------------------------------------------------
// K1: build per-(round,pair) table: {cos, sin, packed (i | j<<16), 0}
// Rounds >= 255 are identity padding (c=1, s=0, pair (0,1)) -> exact no-op.
// One sincos per (round,pair) TOTAL (table is shared by all 64 column-blocks;
// round-2's inline fusion recomputed these 64x on the critical chain and
// turned coalesced table reads into scattered theta gathers -- 43us kernel).
// ---------------------------------------------------------------------------
__global__ void k_prep(const float* __restrict__ thetas, float4* __restrict__ tbl) {
    int idx = blockIdx.x * 256 + threadIdx.x;
    if (idx >= TBL_ROUNDS * 128) return;
    int r = idx >> 7;
    int k = idx & 127;
    if (r >= 255) {
        tbl[idx] = make_float4(1.0f, 0.0f, __int_as_float(0 | (1 << 16)), 0.0f);
        return;
    }
    int i, j;
    if (k == 0) {
        i = 0;
        j = (254 - r) + 1;
    } else {
        int m1 = k - 1 - r;   if (m1 < 0) m1 += 255;
        int m2 = 254 - k - r; if (m2 < 0) m2 += 255;
        int v1 = m1 + 1, v2 = m2 + 1;
        i = v1 < v2 ? v1 : v2;
        j = v1 < v2 ? v2 : v1;
    }
    int tix = i * 256 - (i * (i + 1)) / 2 + (j - i - 1);
    float th = thetas[tix];
    float s, c;
    sincosf(th, &s, &c);
    tbl[idx] = make_float4(c, s, __int_as_float(i | (j << 16)), 0.0f);
}

// ---------------------------------------------------------------------------
// K2: partial rotation products, 4 groups of 64 rounds (round 255 = pad no-op).
// One wave per block, 4 columns in LDS, wave-synchronous (no barriers; per-wave
// LDS ops complete in program order).  Coalesced table loads, depth-4 register
// prefetch ring (64 % 4 == 0 -> static ring slot).  No LDS padding: the 8x
// bank pressure of 64 lanes x b128 is structural (256 bank-words / 32 banks),
// a row permutation cannot reduce it.
// ---------------------------------------------------------------------------
template <int ROFF>
__device__ __forceinline__ void rot_rounds64(const float4* __restrict__ t0, float4* buf) {
    float4 e0[4], e1[4];
#pragma unroll
    for (int d = 0; d < 4; ++d) {
        e0[d] = t0[(ROFF + d) * 128];
        e1[d] = t0[(ROFF + d) * 128 + 1];
    }
#pragma unroll 4
    for (int it = 0; it < 64; ++it) {
        const int slot = it % 4;                  // static under unroll-4
        float4 E0 = e0[slot], E1 = e1[slot];
        // prefetch round it+4 (reads past 255 land in padded tbl region)
        e0[slot] = t0[(ROFF + it + 4) * 128];
        e1[slot] = t0[(ROFF + it + 4) * 128 + 1];

        int ij0 = __float_as_int(E0.z);
        int a0 = ij0 & 0xffff, b0 = ij0 >> 16;
        int ij1 = __float_as_int(E1.z);
        int a1 = ij1 & 0xffff, b1 = ij1 >> 16;

        float4 ra0 = buf[a0], rb0 = buf[b0];
        float4 ra1 = buf[a1], rb1 = buf[b1];
        float4 na0, nb0, na1, nb1;
        na0.x = E0.x * ra0.x - E0.y * rb0.x;
        na0.y = E0.x * ra0.y - E0.y * rb0.y;
        na0.z = E0.x * ra0.z - E0.y * rb0.z;
        na0.w = E0.x * ra0.w - E0.y * rb0.w;
        nb0.x = E0.y * ra0.x + E0.x * rb0.x;
        nb0.y = E0.y * ra0.y + E0.x * rb0.y;
        nb0.z = E0.y * ra0.z + E0.x * rb0.z;
        nb0.w = E0.y * ra0.w + E0.x * rb0.w;
        na1.x = E1.x * ra1.x - E1.y * rb1.x;
        na1.y = E1.x * ra1.y - E1.y * rb1.y;
        na1.z = E1.x * ra1.z - E1.y * rb1.z;
        na1.w = E1.x * ra1.w - E1.y * rb1.w;
        nb1.x = E1.y * ra1.x + E1.x * rb1.x;
        nb1.y = E1.y * ra1.y + E1.x * rb1.y;
        nb1.z = E1.y * ra1.z + E1.x * rb1.z;
        nb1.w = E1.y * ra1.w + E1.x * rb1.w;
        buf[a0] = na0; buf[b0] = nb0;
        buf[a1] = na1; buf[b1] = nb1;
    }
}

__global__ __launch_bounds__(64) void k_rot(const float4* __restrict__ tbl,
                                            float* __restrict__ Rg) {
    __shared__ float4 buf[256];                  // 4 columns of the matrix
    int l   = threadIdx.x;                       // 0..63, one wave per block
    int grp = blockIdx.y;                        // 0..3
    int c0  = blockIdx.x * 4;                    // this block's 4 columns
#pragma unroll
    for (int q = 0; q < 4; ++q) {
        int m = l * 4 + q;
        float4 v = make_float4(0.f, 0.f, 0.f, 0.f);
        if (m == c0)     v.x = 1.f;
        if (m == c0 + 1) v.y = 1.f;
        if (m == c0 + 2) v.z = 1.f;
        if (m == c0 + 3) v.w = 1.f;
        buf[m] = v;                              // identity columns
    }
    const float4* t0 = tbl + 2 * l;              // this lane owns pairs 2l, 2l+1
    if      (grp == 0) rot_rounds64<0>(t0, buf);
    else if (grp == 1) rot_rounds64<64>(t0, buf);
    else if (grp == 2) rot_rounds64<128>(t0, buf);
    else               rot_rounds64<192>(t0, buf);

    float* Rout = Rg + grp * (256 * 256);
#pragma unroll
    for (int q = 0; q < 4; ++q) {
        int m = l * 4 + q;
        *(float4*)(Rout + m * 256 + c0) = buf[m];
    }
}

// ---------------------------------------------------------------------------
// K3: fused 3-stage merge  R = G3 * G2 * G1 * G0.
// 128 blocks x 256 threads; block owns output rows {2b, 2b+1}.
// Wave w = row (w>>1), k-half (w&1).  Per stage: v_row . M with the row
// vector broadcast from LDS, M streamed (coalesced float4), k split across
// 2 waves, partials combined in LDS.  One launch instead of two.
// ---------------------------------------------------------------------------
__global__ __launch_bounds__(256) void k_merge4(const float* __restrict__ Rg,
                                                float* __restrict__ R) {
    __shared__ float vcur[2][256];   // current row vectors (2 rows)
    __shared__ float pacc[4][256];   // per-wave partial sums
    int t = threadIdx.x;
    int w = t >> 6;                  // wave 0..3
    int l = t & 63;
    int row  = w >> 1;               // 0/1 within block
    int half = w & 1;                // k half
    int r0 = blockIdx.x * 2;         // global output rows r0, r0+1

    // init: v = rows of G3
    if (t < 128) {
        int rr = t >> 6, k4 = (t & 63) * 4;
        *(float4*)&vcur[rr][k4] =
            *(const float4*)(Rg + 3 * 65536 + (r0 + rr) * 256 + k4);
    }
    __syncthreads();

    for (int g = 2; g >= 0; --g) {
        const float* A = Rg + g * 65536;
        int kbase = half * 128;
        float4 acc = make_float4(0.f, 0.f, 0.f, 0.f);
#pragma unroll 8
        for (int kk = 0; kk < 128; ++kk) {
            float  s = vcur[row][kbase + kk];              // LDS broadcast
            float4 a = *(const float4*)(A + (kbase + kk) * 256 + l * 4);
            acc.x += s * a.x; acc.y += s * a.y;
            acc.z += s * a.z; acc.w += s * a.w;
        }
        *(float4*)&pacc[w][l * 4] = acc;
        __syncthreads();
        if (t < 128) {
            int rr = t >> 6, c4 = (t & 63) * 4;
            float4 p0 = *(float4*)&pacc[rr * 2 + 0][c4];
            float4 p1 = *(float4*)&pacc[rr * 2 + 1][c4];
            float4 sum = make_float4(p0.x + p1.x, p0.y + p1.y,
                                     p0.z + p1.z, p0.w + p1.w);
            if (g > 0) *(float4*)&vcur[rr][c4] = sum;
            else       *(float4*)(R + (r0 + rr) * 256 + c4) = sum;
        }
        __syncthreads();
    }
}

// ---------------------------------------------------------------------------
// K4: out = R * X  (256x256 @ 256x8192), fp32 vector GEMM.
// Block: 512 threads = 8 waves; tile 64 rows x 128 cols.  A via wave-uniform
// scalar loads (SMEM pipe), X double-buffered in LDS via global_load_lds
// width 16.  1 ds_read_b64 per 16 FMAs -> VALU-bound (~6.8 us floor).
// ---------------------------------------------------------------------------
__global__ __launch_bounds__(512) void k_gemm(const float* __restrict__ R,
                                              const float* __restrict__ X,
                                              float* __restrict__ out) {
    __shared__ __align__(16) float Xs[2][32][128];   // 2 x 16 KB k-chunks
    int t  = threadIdx.x;
    int w  = t >> 6;                                 // wave 0..7
    int l  = t & 63;
    int n0 = blockIdx.x * 128;                       // 64 col-groups
    int m0 = blockIdx.y * 64;                        // 4 row-groups
    int iw = __builtin_amdgcn_readfirstlane(m0 + w * 8);
    const float* Ra = R + iw * 256;                  // wave's 8 A-rows

    float2 acc[8];
#pragma unroll
    for (int r = 0; r < 8; ++r) acc[r] = make_float2(0.f, 0.f);

    auto stage = [&](int bi, int kc) {
        int k0  = kc * 32;
        int kkb = w * 4;
#pragma unroll
        for (int p = 0; p < 2; ++p) {
            int row = kkb + p * 2 + (l >> 5);
            int col = (l & 31) * 4;
            const float* src = X + (size_t)(k0 + row) * NB + n0 + col;
            __builtin_amdgcn_global_load_lds(
                (const __attribute__((address_space(1))) unsigned int*)src,
                (__attribute__((address_space(3))) unsigned int*)&Xs[bi][kkb + p * 2][0],
                16, 0, 0);
        }
    };

    stage(0, 0);
    __syncthreads();                                  // implies vmcnt(0) drain
    int buf = 0;
    for (int kc = 0; kc < 8; ++kc) {
        if (kc < 7) stage(buf ^ 1, kc + 1);           // prefetch next chunk
#pragma unroll
        for (int k4 = 0; k4 < 8; ++k4) {              // 4-k sub-chunks
            float4 ar[8];
#pragma unroll
            for (int r = 0; r < 8; ++r)               // uniform addr -> s_load
                ar[r] = *(const float4*)(Ra + r * 256 + kc * 32 + k4 * 4);
#pragma unroll
            for (int q = 0; q < 4; ++q) {
                float2 x = *(const float2*)&Xs[buf][k4 * 4 + q][l * 2];
#pragma unroll
                for (int r = 0; r < 8; ++r) {
                    float av = (q == 0) ? ar[r].x : (q == 1) ? ar[r].y
                             : (q == 2) ? ar[r].z : ar[r].w;
                    acc[r].x += av * x.x;
                    acc[r].y += av * x.y;
                }
            }
        }
        __syncthreads();                              // staged chunk now visible
        buf ^= 1;
    }
#pragma unroll
    for (int r = 0; r < 8; ++r) {
        *(float2*)(out + (size_t)(iw + r) * NB + n0 + l * 2) = acc[r];
    }
}

// ---------------------------------------------------------------------------
extern "C" void kernel_launch(void* const* d_in, const int* in_sizes, int n_in,
                              void* d_out, int out_size, void* d_ws, size_t ws_size,
                              hipStream_t stream) {
    const float* X      = (const float*)d_in[0];
    const float* thetas = (const float*)d_in[1];
    float* out = (float*)d_out;
    char*  ws  = (char*)d_ws;

    float4* tbl = (float4*)ws;
    float*  Rg  = (float*)(ws + 540672);
    float*  R   = (float*)(ws + 1589248);

    k_prep  <<<dim3(132),   dim3(256), 0, stream>>>(thetas, tbl);
    k_rot   <<<dim3(64, 4), dim3(64),  0, stream>>>(tbl, Rg);
    k_merge4<<<dim3(128),   dim3(256), 0, stream>>>(Rg, R);
    k_gemm  <<<dim3(64, 4), dim3(512), 0, stream>>>(R, X, out);
}

// Round 4
// 59.590 us; speedup vs baseline: 1.4997x; 1.1250x over previous
//
#include <hip/hip_runtime.h>

#define NROT 256
#define NB   8192
#define TBL_ROUNDS 264   // 255 real rounds + identity padding for prefetch ring

// ---------------------------------------------------------------------------
// Workspace layout (bytes):
//   [0,       540672)    cs/ij table: 264 rounds x 128 x float4
//   [540672,  1589248)   Rg: 4 group products (4 x 256x256 f32)
//   [1589248, 1851392)   R : final merged 256x256 f32
// ---------------------------------------------------------------------------

// ---------------------------------------------------------------------------
// K1: build per-(round,pair) table: {cos, sin, packed (i | j<<16), 0}
// Rounds >= 255 are identity padding (c=1, s=0, pair (0,1)) -> exact no-op.
// One sincos per (round,pair) TOTAL (shared by all column-blocks).
// ---------------------------------------------------------------------------
__global__ void k_prep(const float* __restrict__ thetas, float4* __restrict__ tbl) {
    int idx = blockIdx.x * 256 + threadIdx.x;
    if (idx >= TBL_ROUNDS * 128) return;
    int r = idx >> 7;
    int k = idx & 127;
    if (r >= 255) {
        tbl[idx] = make_float4(1.0f, 0.0f, __int_as_float(0 | (1 << 16)), 0.0f);
        return;
    }
    int i, j;
    if (k == 0) {
        i = 0;
        j = (254 - r) + 1;
    } else {
        int m1 = k - 1 - r;   if (m1 < 0) m1 += 255;
        int m2 = 254 - k - r; if (m2 < 0) m2 += 255;
        int v1 = m1 + 1, v2 = m2 + 1;
        i = v1 < v2 ? v1 : v2;
        j = v1 < v2 ? v2 : v1;
    }
    int tix = i * 256 - (i * (i + 1)) / 2 + (j - i - 1);
    float th = thetas[tix];
    float s, c;
    sincosf(th, &s, &c);
    tbl[idx] = make_float4(c, s, __int_as_float(i | (j << 16)), 0.0f);
}

// ---------------------------------------------------------------------------
// K2: partial rotation products, 4 groups of 64 rounds (round 255 = pad no-op).
// ONE COLUMN per block: all LDS ops are conflict-free scalar b32 (64 lanes x
// 1 word = 2 words/bank = free per m136), cutting the serial read->fmac->write
// chain from ~310 cyc/round (float4, 8-phase b128 conflicts) to ~190.
// Grid (256 cols, 4 groups) = 1024 independent chains, 4 per CU.
// Coalesced table loads, depth-4 register prefetch ring (off-chain).
// ---------------------------------------------------------------------------
template <int ROFF>
__device__ __forceinline__ void rot_rounds64(const float4* __restrict__ t0, float* buf) {
    float4 e0[4], e1[4];
#pragma unroll
    for (int d = 0; d < 4; ++d) {
        e0[d] = t0[(ROFF + d) * 128];
        e1[d] = t0[(ROFF + d) * 128 + 1];
    }
#pragma unroll 4
    for (int it = 0; it < 64; ++it) {
        const int slot = it % 4;                  // static under unroll-4
        float4 E0 = e0[slot], E1 = e1[slot];
        // prefetch round it+4 (reads past 255 land in padded tbl region)
        e0[slot] = t0[(ROFF + it + 4) * 128];
        e1[slot] = t0[(ROFF + it + 4) * 128 + 1];

        int ij0 = __float_as_int(E0.z);
        int a0 = ij0 & 0xffff, b0 = ij0 >> 16;
        int ij1 = __float_as_int(E1.z);
        int a1 = ij1 & 0xffff, b1 = ij1 >> 16;

        float ra0 = buf[a0], rb0 = buf[b0];
        float ra1 = buf[a1], rb1 = buf[b1];
        float na0 = E0.x * ra0 - E0.y * rb0;
        float nb0 = E0.y * ra0 + E0.x * rb0;
        float na1 = E1.x * ra1 - E1.y * rb1;
        float nb1 = E1.y * ra1 + E1.x * rb1;
        buf[a0] = na0; buf[b0] = nb0;
        buf[a1] = na1; buf[b1] = nb1;
    }
}

__global__ __launch_bounds__(64) void k_rot(const float4* __restrict__ tbl,
                                            float* __restrict__ Rg) {
    __shared__ float buf[256];                   // ONE column of the matrix
    int l   = threadIdx.x;                       // 0..63, one wave per block
    int grp = blockIdx.y;                        // 0..3
    int c   = blockIdx.x;                        // this block's column
#pragma unroll
    for (int q = 0; q < 4; ++q) {
        int m = l * 4 + q;
        buf[m] = (m == c) ? 1.0f : 0.0f;         // identity column
    }
    const float4* t0 = tbl + 2 * l;              // this lane owns pairs 2l, 2l+1
    if      (grp == 0) rot_rounds64<0>(t0, buf);
    else if (grp == 1) rot_rounds64<64>(t0, buf);
    else if (grp == 2) rot_rounds64<128>(t0, buf);
    else               rot_rounds64<192>(t0, buf);

    float* Rout = Rg + grp * (256 * 256);
#pragma unroll
    for (int q = 0; q < 4; ++q) {
        int m = l * 4 + q;
        Rout[m * 256 + c] = buf[m];              // 4B stores; 1 MB total, L2-merged
    }
}

// ---------------------------------------------------------------------------
// K3: fused 3-stage merge  R = G3 * G2 * G1 * G0.
// 256 blocks x 256 threads; block owns ONE output row (full GPU, was 128
// blocks / half GPU).  Wave w covers k-quarter [64w, 64w+64).  Per stage:
// v_row . M with the row vector broadcast from LDS, M streamed coalesced
// (wave reads a full 1KB row of A per kk), partials combined in LDS.
// ---------------------------------------------------------------------------
__global__ __launch_bounds__(256) void k_merge4(const float* __restrict__ Rg,
                                                float* __restrict__ R) {
    __shared__ float vcur[256];      // current row vector
    __shared__ float pacc[4][256];   // per-wave partial sums
    int t = threadIdx.x;
    int w = t >> 6;                  // wave 0..3 = k-quarter
    int l = t & 63;
    int r0 = blockIdx.x;             // global output row

    // init: v = row r0 of G3
    if (t < 64)
        *(float4*)&vcur[t * 4] =
            *(const float4*)(Rg + 3 * 65536 + r0 * 256 + t * 4);
    __syncthreads();

    for (int g = 2; g >= 0; --g) {
        const float* A = Rg + g * 65536;
        int kbase = w * 64;
        float4 acc = make_float4(0.f, 0.f, 0.f, 0.f);
#pragma unroll 8
        for (int kk = 0; kk < 64; ++kk) {
            float  s = vcur[kbase + kk];                   // LDS broadcast
            float4 a = *(const float4*)(A + (kbase + kk) * 256 + l * 4);
            acc.x += s * a.x; acc.y += s * a.y;
            acc.z += s * a.z; acc.w += s * a.w;
        }
        *(float4*)&pacc[w][l * 4] = acc;
        __syncthreads();
        if (t < 64) {
            float4 p0 = *(float4*)&pacc[0][t * 4];
            float4 p1 = *(float4*)&pacc[1][t * 4];
            float4 p2 = *(float4*)&pacc[2][t * 4];
            float4 p3 = *(float4*)&pacc[3][t * 4];
            float4 sum = make_float4(p0.x + p1.x + p2.x + p3.x,
                                     p0.y + p1.y + p2.y + p3.y,
                                     p0.z + p1.z + p2.z + p3.z,
                                     p0.w + p1.w + p2.w + p3.w);
            if (g > 0) *(float4*)&vcur[t * 4] = sum;
            else       *(float4*)(R + r0 * 256 + t * 4) = sum;
        }
        __syncthreads();
    }
}

// ---------------------------------------------------------------------------
// K4: out = R * X  (256x256 @ 256x8192), fp32 vector GEMM.
// Block: 512 threads = 8 waves; tile 64 rows x 128 cols.  A via wave-uniform
// scalar loads (SMEM pipe), X double-buffered in LDS via global_load_lds
// width 16.  1 ds_read_b64 per 16 FMAs -> VALU-bound (~6.8 us floor).
// ---------------------------------------------------------------------------
__global__ __launch_bounds__(512) void k_gemm(const float* __restrict__ R,
                                              const float* __restrict__ X,
                                              float* __restrict__ out) {
    __shared__ __align__(16) float Xs[2][32][128];   // 2 x 16 KB k-chunks
    int t  = threadIdx.x;
    int w  = t >> 6;                                 // wave 0..7
    int l  = t & 63;
    int n0 = blockIdx.x * 128;                       // 64 col-groups
    int m0 = blockIdx.y * 64;                        // 4 row-groups
    int iw = __builtin_amdgcn_readfirstlane(m0 + w * 8);
    const float* Ra = R + iw * 256;                  // wave's 8 A-rows

    float2 acc[8];
#pragma unroll
    for (int r = 0; r < 8; ++r) acc[r] = make_float2(0.f, 0.f);

    auto stage = [&](int bi, int kc) {
        int k0  = kc * 32;
        int kkb = w * 4;
#pragma unroll
        for (int p = 0; p < 2; ++p) {
            int row = kkb + p * 2 + (l >> 5);
            int col = (l & 31) * 4;
            const float* src = X + (size_t)(k0 + row) * NB + n0 + col;
            __builtin_amdgcn_global_load_lds(
                (const __attribute__((address_space(1))) unsigned int*)src,
                (__attribute__((address_space(3))) unsigned int*)&Xs[bi][kkb + p * 2][0],
                16, 0, 0);
        }
    };

    stage(0, 0);
    __syncthreads();                                  // implies vmcnt(0) drain
    int buf = 0;
    for (int kc = 0; kc < 8; ++kc) {
        if (kc < 7) stage(buf ^ 1, kc + 1);           // prefetch next chunk
#pragma unroll
        for (int k4 = 0; k4 < 8; ++k4) {              // 4-k sub-chunks
            float4 ar[8];
#pragma unroll
            for (int r = 0; r < 8; ++r)               // uniform addr -> s_load
                ar[r] = *(const float4*)(Ra + r * 256 + kc * 32 + k4 * 4);
#pragma unroll
            for (int q = 0; q < 4; ++q) {
                float2 x = *(const float2*)&Xs[buf][k4 * 4 + q][l * 2];
#pragma unroll
                for (int r = 0; r < 8; ++r) {
                    float av = (q == 0) ? ar[r].x : (q == 1) ? ar[r].y
                             : (q == 2) ? ar[r].z : ar[r].w;
                    acc[r].x += av * x.x;
                    acc[r].y += av * x.y;
                }
            }
        }
        __syncthreads();                              // staged chunk now visible
        buf ^= 1;
    }
#pragma unroll
    for (int r = 0; r < 8; ++r) {
        *(float2*)(out + (size_t)(iw + r) * NB + n0 + l * 2) = acc[r];
    }
}

// ---------------------------------------------------------------------------
extern "C" void kernel_launch(void* const* d_in, const int* in_sizes, int n_in,
                              void* d_out, int out_size, void* d_ws, size_t ws_size,
                              hipStream_t stream) {
    const float* X      = (const float*)d_in[0];
    const float* thetas = (const float*)d_in[1];
    float* out = (float*)d_out;
    char*  ws  = (char*)d_ws;

    float4* tbl = (float4*)ws;
    float*  Rg  = (float*)(ws + 540672);
    float*  R   = (float*)(ws + 1589248);

    k_prep  <<<dim3(132),    dim3(256), 0, stream>>>(thetas, tbl);
    k_rot   <<<dim3(256, 4), dim3(64),  0, stream>>>(tbl, Rg);
    k_merge4<<<dim3(256),    dim3(256), 0, stream>>>(Rg, R);
    k_gemm  <<<dim3(64, 4),  dim3(512), 0, stream>>>(R, X, out);
}

// Round 5
// 39.419 us; speedup vs baseline: 2.2672x; 1.5117x over previous
//
#include <hip/hip_runtime.h>

#define NROT 256
#define NB   8192
#define TBL_ROUNDS 264   // 255 real rounds + identity padding for prefetch ring

typedef _Float16 f16;
typedef _Float16 f16x8 __attribute__((ext_vector_type(8)));
typedef float    f32x4 __attribute__((ext_vector_type(4)));

// ---------------------------------------------------------------------------
// Workspace layout (bytes):
//   [0,       540672)    cs/ij table: 264 rounds x 128 x float4
//   [540672,  1589248)   Rg: 4 group products (4 x 256x256 f32)
//   [1589248, 1720320)   Rh: merged R in fp16 (256x256 halves)
// ---------------------------------------------------------------------------

// ---------------------------------------------------------------------------
// K1: build per-(round,pair) table: {cos, sin, packed (i | j<<16), 0}
// Rounds >= 255 are identity padding (c=1, s=0, pair (0,1)) -> exact no-op.
// ---------------------------------------------------------------------------
__global__ void k_prep(const float* __restrict__ thetas, float4* __restrict__ tbl) {
    int idx = blockIdx.x * 256 + threadIdx.x;
    if (idx >= TBL_ROUNDS * 128) return;
    int r = idx >> 7;
    int k = idx & 127;
    if (r >= 255) {
        tbl[idx] = make_float4(1.0f, 0.0f, __int_as_float(0 | (1 << 16)), 0.0f);
        return;
    }
    int i, j;
    if (k == 0) {
        i = 0;
        j = (254 - r) + 1;
    } else {
        int m1 = k - 1 - r;   if (m1 < 0) m1 += 255;
        int m2 = 254 - k - r; if (m2 < 0) m2 += 255;
        int v1 = m1 + 1, v2 = m2 + 1;
        i = v1 < v2 ? v1 : v2;
        j = v1 < v2 ? v2 : v1;
    }
    int tix = i * 256 - (i * (i + 1)) / 2 + (j - i - 1);
    float th = thetas[tix];
    float s, c;
    sincosf(th, &s, &c);
    tbl[idx] = make_float4(c, s, __int_as_float(i | (j << 16)), 0.0f);
}

// ---------------------------------------------------------------------------
// K2: partial rotation products, 4 groups of 64 rounds (round 255 = pad no-op).
// ONE COLUMN per block: all LDS ops conflict-free scalar b32.  Grid (256,4) =
// 1024 independent chains, 4/CU.  Depth-4 table prefetch ring (off-chain).
// ---------------------------------------------------------------------------
template <int ROFF>
__device__ __forceinline__ void rot_rounds64(const float4* __restrict__ t0, float* buf) {
    float4 e0[4], e1[4];
#pragma unroll
    for (int d = 0; d < 4; ++d) {
        e0[d] = t0[(ROFF + d) * 128];
        e1[d] = t0[(ROFF + d) * 128 + 1];
    }
#pragma unroll 4
    for (int it = 0; it < 64; ++it) {
        const int slot = it % 4;                  // static under unroll-4
        float4 E0 = e0[slot], E1 = e1[slot];
        e0[slot] = t0[(ROFF + it + 4) * 128];
        e1[slot] = t0[(ROFF + it + 4) * 128 + 1];

        int ij0 = __float_as_int(E0.z);
        int a0 = ij0 & 0xffff, b0 = ij0 >> 16;
        int ij1 = __float_as_int(E1.z);
        int a1 = ij1 & 0xffff, b1 = ij1 >> 16;

        float ra0 = buf[a0], rb0 = buf[b0];
        float ra1 = buf[a1], rb1 = buf[b1];
        float na0 = E0.x * ra0 - E0.y * rb0;
        float nb0 = E0.y * ra0 + E0.x * rb0;
        float na1 = E1.x * ra1 - E1.y * rb1;
        float nb1 = E1.y * ra1 + E1.x * rb1;
        buf[a0] = na0; buf[b0] = nb0;
        buf[a1] = na1; buf[b1] = nb1;
    }
}

__global__ __launch_bounds__(64) void k_rot(const float4* __restrict__ tbl,
                                            float* __restrict__ Rg) {
    __shared__ float buf[256];                   // ONE column of the matrix
    int l   = threadIdx.x;
    int grp = blockIdx.y;                        // 0..3
    int c   = blockIdx.x;                        // this block's column
#pragma unroll
    for (int q = 0; q < 4; ++q) {
        int m = l * 4 + q;
        buf[m] = (m == c) ? 1.0f : 0.0f;
    }
    const float4* t0 = tbl + 2 * l;
    if      (grp == 0) rot_rounds64<0>(t0, buf);
    else if (grp == 1) rot_rounds64<64>(t0, buf);
    else if (grp == 2) rot_rounds64<128>(t0, buf);
    else               rot_rounds64<192>(t0, buf);

    float* Rout = Rg + grp * (256 * 256);
#pragma unroll
    for (int q = 0; q < 4; ++q) {
        int m = l * 4 + q;
        Rout[m * 256 + c] = buf[m];
    }
}

// ---------------------------------------------------------------------------
// K3: fused 3-stage merge  R = G3*G2*G1*G0, output in FP16 for the MFMA gemm.
// 256 blocks x 256 threads; block owns ONE output row.  Wave w = k-quarter.
// ---------------------------------------------------------------------------
__global__ __launch_bounds__(256) void k_merge4(const float* __restrict__ Rg,
                                                f16* __restrict__ Rh) {
    __shared__ float vcur[256];
    __shared__ float pacc[4][256];
    int t = threadIdx.x;
    int w = t >> 6;
    int l = t & 63;
    int r0 = blockIdx.x;

    if (t < 64)
        *(float4*)&vcur[t * 4] =
            *(const float4*)(Rg + 3 * 65536 + r0 * 256 + t * 4);
    __syncthreads();

    for (int g = 2; g >= 0; --g) {
        const float* A = Rg + g * 65536;
        int kbase = w * 64;
        float4 acc = make_float4(0.f, 0.f, 0.f, 0.f);
#pragma unroll 8
        for (int kk = 0; kk < 64; ++kk) {
            float  s = vcur[kbase + kk];
            float4 a = *(const float4*)(A + (kbase + kk) * 256 + l * 4);
            acc.x += s * a.x; acc.y += s * a.y;
            acc.z += s * a.z; acc.w += s * a.w;
        }
        *(float4*)&pacc[w][l * 4] = acc;
        __syncthreads();
        if (t < 64) {
            float4 p0 = *(float4*)&pacc[0][t * 4];
            float4 p1 = *(float4*)&pacc[1][t * 4];
            float4 p2 = *(float4*)&pacc[2][t * 4];
            float4 p3 = *(float4*)&pacc[3][t * 4];
            float4 sum = make_float4(p0.x + p1.x + p2.x + p3.x,
                                     p0.y + p1.y + p2.y + p3.y,
                                     p0.z + p1.z + p2.z + p3.z,
                                     p0.w + p1.w + p2.w + p3.w);
            if (g > 0) *(float4*)&vcur[t * 4] = sum;
            else {
                int o = r0 * 256 + t * 4;
                Rh[o + 0] = (f16)sum.x;
                Rh[o + 1] = (f16)sum.y;
                Rh[o + 2] = (f16)sum.z;
                Rh[o + 3] = (f16)sum.w;
            }
        }
        __syncthreads();
    }
}

// ---------------------------------------------------------------------------
// K4: out = R * X via FP16 MFMA (mfma_f32_16x16x32_f16, fp32 accumulate).
// Grid 256 blocks (N-slice of 32 cols), 512 threads = 8 waves; wave w owns
// rows [32w, 32w+32) -> 2x2 16x16 acc frags, K=256 in 8 steps.
// X staged once per block: fp32 tile [256k][32n] (coalesced) -> fp16
// k-major LDS Xh[n][k ^ ((n&7)*8 halves)] (XOR swizzle -> B-frag
// ds_read_b128 at the 8-cycle bank floor).  A-frags read directly from the
// fp16 R (L2-hot, 128 KB).  k-mapping (k = 8*(lane>>4)+j) used identically
// for A and B -> contraction correct under any shared k-permutation.
// ---------------------------------------------------------------------------
__global__ __launch_bounds__(512) void k_gemm(const f16* __restrict__ Rh,
                                              const float* __restrict__ X,
                                              float* __restrict__ out) {
    __shared__ float Xf[256][32];                    // 32 KB fp32 staging
    __shared__ __align__(16) f16 Xh[32 * 256];       // 16 KB fp16 k-major
    int t  = threadIdx.x;
    int w  = t >> 6;                                 // wave 0..7
    int l  = t & 63;
    int n0 = blockIdx.x * 32;

    // phase A: global -> Xf (coalesced float4)
#pragma unroll
    for (int p = 0; p < 4; ++p) {
        int idx = t + 512 * p;                       // 0..2047
        int n4  = idx & 7;
        int k   = idx >> 3;
        *(float4*)&Xf[k][n4 * 4] =
            *(const float4*)(X + (size_t)k * NB + n0 + n4 * 4);
    }
    __syncthreads();

    // phase B: Xf -> fp16 k-major swizzled Xh (reads bank-spread by n)
    {
        int n  = t & 31;
        int k0 = (t >> 5) * 16;
        f16x8 h0, h1;
#pragma unroll
        for (int u = 0; u < 8; ++u) h0[u] = (f16)Xf[k0 + u][n];
#pragma unroll
        for (int u = 0; u < 8; ++u) h1[u] = (f16)Xf[k0 + 8 + u][n];
        int xv = (n & 7) * 8;
        *(f16x8*)&Xh[n * 256 + ((k0    ) ^ xv)] = h0;
        *(f16x8*)&Xh[n * 256 + ((k0 + 8) ^ xv)] = h1;
    }
    __syncthreads();

    f32x4 acc[2][2];
#pragma unroll
    for (int r = 0; r < 2; ++r)
#pragma unroll
        for (int c = 0; c < 2; ++c) acc[r][c] = (f32x4){0.f, 0.f, 0.f, 0.f};

    int lm = l & 15;
    int g  = l >> 4;
    int xv = (lm & 7) * 8;
#pragma unroll
    for (int s = 0; s < 8; ++s) {
        int koff = s * 32 + 8 * g;
        f16x8 a0 = *(const f16x8*)(Rh + (32 * w + lm) * 256 + koff);
        f16x8 a1 = *(const f16x8*)(Rh + (32 * w + 16 + lm) * 256 + koff);
        f16x8 b0 = *(const f16x8*)&Xh[lm * 256        + (koff ^ xv)];
        f16x8 b1 = *(const f16x8*)&Xh[(16 + lm) * 256 + (koff ^ xv)];
        acc[0][0] = __builtin_amdgcn_mfma_f32_16x16x32_f16(a0, b0, acc[0][0], 0, 0, 0);
        acc[0][1] = __builtin_amdgcn_mfma_f32_16x16x32_f16(a0, b1, acc[0][1], 0, 0, 0);
        acc[1][0] = __builtin_amdgcn_mfma_f32_16x16x32_f16(a1, b0, acc[1][0], 0, 0, 0);
        acc[1][1] = __builtin_amdgcn_mfma_f32_16x16x32_f16(a1, b1, acc[1][1], 0, 0, 0);
    }

    // C/D layout: col = lane&15, row = (lane>>4)*4 + reg
#pragma unroll
    for (int r = 0; r < 2; ++r)
#pragma unroll
        for (int c = 0; c < 2; ++c)
#pragma unroll
            for (int q = 0; q < 4; ++q)
                out[(size_t)(32 * w + 16 * r + 4 * g + q) * NB + n0 + 16 * c + lm] =
                    acc[r][c][q];
}

// ---------------------------------------------------------------------------
extern "C" void kernel_launch(void* const* d_in, const int* in_sizes, int n_in,
                              void* d_out, int out_size, void* d_ws, size_t ws_size,
                              hipStream_t stream) {
    const float* X      = (const float*)d_in[0];
    const float* thetas = (const float*)d_in[1];
    float* out = (float*)d_out;
    char*  ws  = (char*)d_ws;

    float4* tbl = (float4*)ws;
    float*  Rg  = (float*)(ws + 540672);
    f16*    Rh  = (f16*)(ws + 1589248);

    k_prep  <<<dim3(132),    dim3(256), 0, stream>>>(thetas, tbl);
    k_rot   <<<dim3(256, 4), dim3(64),  0, stream>>>(tbl, Rg);
    k_merge4<<<dim3(256),    dim3(256), 0, stream>>>(Rg, Rh);
    k_gemm  <<<dim3(256),    dim3(512), 0, stream>>>(Rh, X, out);
}